// Round 6
// baseline (131.003 us; speedup 1.0000x reference)
//
#include <hip/hip_runtime.h>

// Problem constants: N=4, C=320, H=W=D=16 -> L=4096, POS_RATIO=0.5
#define LVOX   4096
#define NCH    320
#define NCOMBO 8        // 4 batches x 2 branches (normal, batch-flipped q)
#define RCAP   49152    // runs per combo; realistic worst ~37K
#define PKSTR  17       // prefix-sum entries per (x,y) cell (exclusive, 0..16)
#define PKROW  (256 * PKSTR)
#define NBLK   (2 * NCH)        // gather blocks = 640
#define RUNS_OFF  128           // byte offset of runs[] in ws

struct Geo {
    float qs0, qs1, qs2, qo0, qo1, qo2;
    float ks0, ks1, ks2, ko0, ko1, ko2;
    float ik0, ik1, ik2;
    float T;
};

// max_diag uses UNFLIPPED diag_q[n] even in the flipped branch (ref computes it pre-flip).
__device__ __forceinline__ Geo make_geo(const float* __restrict__ cq,
                                        const float* __restrict__ ck,
                                        int n, int qb) {
    Geo g;
    const float* qc = cq + qb * 6;
    const float* qn = cq + n * 6;
    const float* kc = ck + n * 6;
    g.qs0 = (qc[3] - qc[0]) * (1.f / 16.f); g.qo0 = qc[0];
    g.qs1 = (qc[4] - qc[1]) * (1.f / 16.f); g.qo1 = qc[1];
    g.qs2 = (qc[5] - qc[2]) * (1.f / 16.f); g.qo2 = qc[2];
    g.ks0 = (kc[3] - kc[0]) * (1.f / 16.f); g.ko0 = kc[0];
    g.ks1 = (kc[4] - kc[1]) * (1.f / 16.f); g.ko1 = kc[1];
    g.ks2 = (kc[5] - kc[2]) * (1.f / 16.f); g.ko2 = kc[2];
    g.ik0 = 1.f / g.ks0; g.ik1 = 1.f / g.ks1; g.ik2 = 1.f / g.ks2;
    float b0 = (qn[3] - qn[0]) * (1.f / 16.f);
    float b1 = (qn[4] - qn[1]) * (1.f / 16.f);
    float b2 = (qn[5] - qn[2]) * (1.f / 16.f);
    float dq = sqrtf(b0 * b0 + b1 * b1 + b2 * b2);
    float dk = sqrtf(g.ks0 * g.ks0 + g.ks1 * g.ks1 + g.ks2 * g.ks2);
    g.T = 0.5f * fmaxf(dq, dk);
    return g;
}

__device__ __forceinline__ void axrange(float c, float ko, float ik, float T,
                                        int& m0, int& m1) {
    float lo = (c - T - ko) * ik - 0.5f;
    float hi = (c + T - ko) * ik - 0.5f;
    m0 = max((int)ceilf(lo) - 1, 0);
    m1 = min((int)floorf(hi) + 1, 15);
}

// One THREAD per (combo, l); emits one RUN per masked (x,y) cell:
//   record = (l<<16) | (m<<4) | (len-1),  m = (x<<8)|(y<<4)|z_first
// Exact per-z sqrtf(...)<T test -> mask identical to reference.
__global__ void enum_runs(const float* __restrict__ coord_q,
                          const float* __restrict__ coord_k,
                          unsigned* __restrict__ pcnt,
                          unsigned* __restrict__ rcnt,
                          unsigned* __restrict__ runs, int cap) {
    int gid = blockIdx.x * 256 + threadIdx.x;   // 8*4096 threads
    int j = gid >> 12;
    int l = gid & 4095;
    int n = j & 3;
    int qb = (j & 4) ? (3 - n) : n;
    Geo g = make_geo(coord_q, coord_k, n, qb);

    int ix = l >> 8, iy = (l >> 4) & 15, iz = l & 15;
    float cx = (ix + 0.5f) * g.qs0 + g.qo0;
    float cy = (iy + 0.5f) * g.qs1 + g.qo1;
    float cz = (iz + 0.5f) * g.qs2 + g.qo2;
    int x0, x1, y0, y1, z0, z1;
    axrange(cx, g.ko0, g.ik0, g.T, x0, x1);
    axrange(cy, g.ko1, g.ik1, g.T, y0, y1);
    axrange(cz, g.ko2, g.ik2, g.T, z0, z1);

    int nh = 0, nr = 0;
    for (int x = x0; x <= x1; ++x) {
        float dx = cx - ((x + 0.5f) * g.ks0 + g.ko0);
        float dx2 = dx * dx;
        for (int y = y0; y <= y1; ++y) {
            float dy = cy - ((y + 0.5f) * g.ks1 + g.ko1);
            float dxy = dx2 + dy * dy;
            int zc = 0;
            for (int z = z0; z <= z1; ++z) {
                float dz = cz - ((z + 0.5f) * g.ks2 + g.ko2);
                if (sqrtf(dxy + dz * dz) < g.T) zc++;
            }
            if (zc) { nr++; nh += zc; }
        }
    }

    int lane = threadIdx.x & 63;
    int incl = nr;
#pragma unroll
    for (int off = 1; off < 64; off <<= 1) {
        int t = __shfl_up(incl, off, 64);
        if (lane >= off) incl += t;
    }
    int total = __shfl(incl, 63, 64);
    int base = 0;
    if (lane == 63) base = (int)atomicAdd(&rcnt[j], (unsigned)total);
    base = __shfl(base, 63, 64);
    int w = base + incl - nr;

    int hsum = nh;
#pragma unroll
    for (int off = 32; off; off >>= 1) hsum += __shfl_down(hsum, off, 64);
    if (lane == 0) atomicAdd(&pcnt[j], (unsigned)hsum);

    unsigned* out = runs + (size_t)j * (size_t)cap;
    for (int x = x0; x <= x1; ++x) {
        float dx = cx - ((x + 0.5f) * g.ks0 + g.ko0);
        float dx2 = dx * dx;
        for (int y = y0; y <= y1; ++y) {
            float dy = cy - ((y + 0.5f) * g.ks1 + g.ko1);
            float dxy = dx2 + dy * dy;
            int zf = -1, zc = 0;
            for (int z = z0; z <= z1; ++z) {
                float dz = cz - ((z + 0.5f) * g.ks2 + g.ko2);
                if (sqrtf(dxy + dz * dz) < g.T) { if (!zc) zf = z; zc++; }
            }
            if (zc) {
                if (w < cap)
                    out[w] = ((unsigned)l << 16)
                           | ((unsigned)((x << 8) | (y << 4) | zf) << 4)
                           | (unsigned)(zc - 1);
                w++;
            }
        }
    }
}

// Fused gather + finalize: one block per (group g, channel c). Group g=0 ->
// batches {0,3}, g=1 -> {1,2}; combos {n0, n1, 4+n0, 4+n1} form a closed set
// over rows {q[n0,c], q[n1,c], k[n0,c], k[n1,c]} -> each row staged ONCE.
// k rows stored as per-(x,y)-cell exclusive z-prefix sums (stride 17,
// conflict-free): run sum = pk[zf+len] - pk[zf]. Partial sums go to S[j] via
// device-scope atomics; the LAST block (done-counter) computes the output.
__global__ void __launch_bounds__(512) gather_fused(
        const float* __restrict__ q, const float* __restrict__ k,
        const unsigned* __restrict__ rcnt, const unsigned* __restrict__ runs,
        int cap, float* __restrict__ S, const unsigned* __restrict__ pcnt,
        unsigned* __restrict__ done, float* __restrict__ out) {
    // sh layout: qa[4096] | qb[4096] | pkA[PKROW] | pkB[PKROW] | sred[32]
    __shared__ float sh[2 * LVOX + 2 * PKROW + 32];
    const int QA = 0, QB = LVOX, PK = 2 * LVOX, SR = 2 * LVOX + 2 * PKROW;

    int g = blockIdx.x;              // 0 or 1
    int c = blockIdx.y;
    int n0 = g ? 1 : 0;
    int n1 = 3 - n0;
    int t = threadIdx.x;

    // stage q rows (coalesced float4)
    const float* q0 = q + ((size_t)(n0 * NCH + c)) * LVOX;
    const float* q1 = q + ((size_t)(n1 * NCH + c)) * LVOX;
#pragma unroll
    for (int i = 0; i < 2; ++i) {
        int off = (t + 512 * i) * 4;
        *(float4*)&sh[QA + off] = *(const float4*)&q0[off];
        *(float4*)&sh[QB + off] = *(const float4*)&q1[off];
    }

    // stage k rows as exclusive z-prefix per cell: thread t owns one cell
    {
        int row = t >> 8;            // 0 -> k[n0], 1 -> k[n1]
        int cl  = t & 255;
        const float* ks = k + ((size_t)((row ? n1 : n0) * NCH + c)) * LVOX + cl * 16;
        float4 v0 = *(const float4*)&ks[0];
        float4 v1 = *(const float4*)&ks[4];
        float4 v2 = *(const float4*)&ks[8];
        float4 v3 = *(const float4*)&ks[12];
        float vv[16] = {v0.x, v0.y, v0.z, v0.w, v1.x, v1.y, v1.z, v1.w,
                        v2.x, v2.y, v2.z, v2.w, v3.x, v3.y, v3.z, v3.w};
        float* dst = &sh[PK + row * PKROW + cl * PKSTR];
        float e = 0.f;
        dst[0] = 0.f;
#pragma unroll
        for (int i = 0; i < 16; ++i) { e += vv[i]; dst[i + 1] = e; }
    }
    __syncthreads();

    const int jl[4]   = {n0, n1, 4 + n0, 4 + n1};
    const int qoff[4] = {QA, QB, QB, QA};              // combo 4+n uses q[3-n]
    const int koff[4] = {PK, PK + PKROW, PK, PK + PKROW};
    float accv[4];

#pragma unroll
    for (int ci = 0; ci < 4; ++ci) {
        int j = jl[ci];
        unsigned cnt = rcnt[j];
        if (cnt > (unsigned)cap) cnt = (unsigned)cap;
        const unsigned* rl = runs + (size_t)j * (size_t)cap;
        int qb = qoff[ci], kb = koff[ci];
        float acc = 0.f;
        for (unsigned p = (unsigned)t * 4u; p < cnt; p += 512u * 4u) {
            uint4 r4 = *(const uint4*)&rl[p];   // cap%4==0 -> in-bounds
            unsigned rr[4] = {r4.x, r4.y, r4.z, r4.w};
#pragma unroll
            for (int e = 0; e < 4; ++e) {
                bool valid = (p + (unsigned)e) < cnt;
                unsigned pr = rr[e];
                int l    = (int)(pr >> 16);
                int cell = (int)((pr >> 8) & 255u);
                int zf   = (int)((pr >> 4) & 15u);
                int len  = (int)(pr & 15u) + 1;
                float s = sh[kb + cell * PKSTR + zf + len] - sh[kb + cell * PKSTR + zf];
                acc += valid ? sh[qb + l] * s : 0.f;
            }
        }
        accv[ci] = acc;
    }

    int wv = t >> 6, lane = t & 63;
#pragma unroll
    for (int ci = 0; ci < 4; ++ci) {
        float a = accv[ci];
#pragma unroll
        for (int off = 32; off; off >>= 1) a += __shfl_down(a, off, 64);
        if (lane == 0) sh[SR + wv * 4 + ci] = a;
    }
    __syncthreads();
    if (t < 4) {
        float v = 0.f;
#pragma unroll
        for (int w = 0; w < 8; ++w) v += sh[SR + w * 4 + t];
        atomicAdd(&S[jl[t]], v);     // device-scope: coherent at L2 point
    }
    __syncthreads();

    // last-block finalize (device-scope done counter; cross-XCD safe)
    if (t == 0) {
        __threadfence();
        unsigned prev = atomicAdd(done, 1u);
        if (prev == (unsigned)(NBLK - 1)) {
            __threadfence();
            float tt = 0.f;
#pragma unroll
            for (int jj = 0; jj < NCOMBO; ++jj) {
                float sj = atomicAdd(&S[jj], 0.f);   // atomic read: L2-coherent
                tt += sj / ((float)pcnt[jj] + 1e-6f);
            }
            out[0] = -0.5f * tt;   // -2*mean over 4 batches, x2 branches
        }
    }
}

extern "C" void kernel_launch(void* const* d_in, const int* in_sizes, int n_in,
                              void* d_out, int out_size, void* d_ws, size_t ws_size,
                              hipStream_t stream) {
    const float* q       = (const float*)d_in[0];
    const float* k       = (const float*)d_in[1];
    const float* coord_q = (const float*)d_in[2];
    const float* coord_k = (const float*)d_in[3];
    float* out = (float*)d_out;

    // ws: [S[8] f32 | pcnt[8] u32 | rcnt[8] u32 | done u32 | pad to 128] [runs 8*cap]
    float*    S    = (float*)d_ws;
    unsigned* pcnt = (unsigned*)d_ws + 8;
    unsigned* rcnt = (unsigned*)d_ws + 16;
    unsigned* done = (unsigned*)d_ws + 24;
    unsigned* runs = (unsigned*)((char*)d_ws + RUNS_OFF);

    size_t avail = (ws_size > RUNS_OFF) ? ((ws_size - RUNS_OFF) / 4) / NCOMBO : 4;
    avail &= ~(size_t)3;                                  // cap % 4 == 0
    int cap = (int)((avail < (size_t)RCAP) ? avail : (size_t)RCAP);
    if (cap < 4) cap = 4;

    hipMemsetAsync(d_ws, 0, 128, stream);
    enum_runs<<<(NCOMBO * LVOX) / 256, 256, 0, stream>>>(coord_q, coord_k, pcnt, rcnt, runs, cap);
    gather_fused<<<dim3(2, NCH), 512, 0, stream>>>(q, k, rcnt, runs, cap, S, pcnt, done, out);
}

// Round 7
// 124.550 us; speedup vs baseline: 1.0518x; 1.0518x over previous
//
#include <hip/hip_runtime.h>

// Problem constants: N=4, C=320, H=W=D=16 -> L=4096, POS_RATIO=0.5
#define LVOX   4096
#define NCH    320
#define NCOMBO 8        // 4 batches x 2 branches (normal, batch-flipped q)
#define NSEG   64       // enum waves per combo (4096 threads / 64 lanes)
#define SEGCAP 4096     // run slots per segment (worst case ~36 runs/thread * 64 = 2304)
#define PKSTR  17       // prefix-sum entries per (x,y) cell (exclusive, 0..16)
#define PKROW  (256 * PKSTR)
#define NBLK   (2 * NCH)        // gather blocks = 640
// ws layout (all deterministically overwritten, no zeroing needed):
//   wcnt  [8*64] u32   @ 0
//   wpcnt [8*64] u32   @ 2048
//   Spart [8*NBLK] f32 @ 4096   (only slot (j, c*2+gj) written/read)
//   runs  [8*64*SEGCAP] u32 @ 24576 (16B aligned)
#define WPCNT_OFF 2048
#define SPART_OFF 4096
#define RUNS_OFF  24576

struct Geo {
    float qs0, qs1, qs2, qo0, qo1, qo2;
    float ks0, ks1, ks2, ko0, ko1, ko2;
    float ik0, ik1, ik2;
    float T;
};

// max_diag uses UNFLIPPED diag_q[n] even in the flipped branch (ref computes it pre-flip).
__device__ __forceinline__ Geo make_geo(const float* __restrict__ cq,
                                        const float* __restrict__ ck,
                                        int n, int qb) {
    Geo g;
    const float* qc = cq + qb * 6;
    const float* qn = cq + n * 6;
    const float* kc = ck + n * 6;
    g.qs0 = (qc[3] - qc[0]) * (1.f / 16.f); g.qo0 = qc[0];
    g.qs1 = (qc[4] - qc[1]) * (1.f / 16.f); g.qo1 = qc[1];
    g.qs2 = (qc[5] - qc[2]) * (1.f / 16.f); g.qo2 = qc[2];
    g.ks0 = (kc[3] - kc[0]) * (1.f / 16.f); g.ko0 = kc[0];
    g.ks1 = (kc[4] - kc[1]) * (1.f / 16.f); g.ko1 = kc[1];
    g.ks2 = (kc[5] - kc[2]) * (1.f / 16.f); g.ko2 = kc[2];
    g.ik0 = 1.f / g.ks0; g.ik1 = 1.f / g.ks1; g.ik2 = 1.f / g.ks2;
    float b0 = (qn[3] - qn[0]) * (1.f / 16.f);
    float b1 = (qn[4] - qn[1]) * (1.f / 16.f);
    float b2 = (qn[5] - qn[2]) * (1.f / 16.f);
    float dq = sqrtf(b0 * b0 + b1 * b1 + b2 * b2);
    float dk = sqrtf(g.ks0 * g.ks0 + g.ks1 * g.ks1 + g.ks2 * g.ks2);
    g.T = 0.5f * fmaxf(dq, dk);
    return g;
}

__device__ __forceinline__ void axrange(float c, float ko, float ik, float T,
                                        int& m0, int& m1) {
    float lo = (c - T - ko) * ik - 0.5f;
    float hi = (c + T - ko) * ik - 0.5f;
    m0 = max((int)ceilf(lo) - 1, 0);
    m1 = min((int)floorf(hi) + 1, 15);
}

// One THREAD per (combo, l); emits one RUN per masked (x,y) cell:
//   record = (l<<16) | (m<<4) | (len-1),  m = (x<<8)|(y<<4)|z_first
// Exact per-z sqrtf(...)<T test -> mask identical to reference.
// Wave w of combo j owns segment (j*64+w): runs via in-wave prefix scan,
// counts via plain stores. NO global atomics, NO pre-zeroed memory.
__global__ void enum_runs(const float* __restrict__ coord_q,
                          const float* __restrict__ coord_k,
                          unsigned* __restrict__ wcnt,
                          unsigned* __restrict__ wpcnt,
                          unsigned* __restrict__ runs) {
    int gid = blockIdx.x * 256 + threadIdx.x;   // 8*4096 threads
    int j = gid >> 12;
    int l = gid & 4095;
    int seg = j * NSEG + ((gid & 4095) >> 6);   // wave-uniform
    int n = j & 3;
    int qb = (j & 4) ? (3 - n) : n;
    Geo g = make_geo(coord_q, coord_k, n, qb);

    int ix = l >> 8, iy = (l >> 4) & 15, iz = l & 15;
    float cx = (ix + 0.5f) * g.qs0 + g.qo0;
    float cy = (iy + 0.5f) * g.qs1 + g.qo1;
    float cz = (iz + 0.5f) * g.qs2 + g.qo2;
    int x0, x1, y0, y1, z0, z1;
    axrange(cx, g.ko0, g.ik0, g.T, x0, x1);
    axrange(cy, g.ko1, g.ik1, g.T, y0, y1);
    axrange(cz, g.ko2, g.ik2, g.T, z0, z1);

    // pass 1: count runs and hits
    int nh = 0, nr = 0;
    for (int x = x0; x <= x1; ++x) {
        float dx = cx - ((x + 0.5f) * g.ks0 + g.ko0);
        float dx2 = dx * dx;
        for (int y = y0; y <= y1; ++y) {
            float dy = cy - ((y + 0.5f) * g.ks1 + g.ko1);
            float dxy = dx2 + dy * dy;
            int zc = 0;
            for (int z = z0; z <= z1; ++z) {
                float dz = cz - ((z + 0.5f) * g.ks2 + g.ko2);
                if (sqrtf(dxy + dz * dz) < g.T) zc++;
            }
            if (zc) { nr++; nh += zc; }
        }
    }

    // in-wave exclusive position via inclusive shuffle scan
    int lane = threadIdx.x & 63;
    int incl = nr;
#pragma unroll
    for (int off = 1; off < 64; off <<= 1) {
        int t = __shfl_up(incl, off, 64);
        if (lane >= off) incl += t;
    }
    int w = incl - nr;                          // exclusive prefix within segment
    if (lane == 63) wcnt[seg] = (unsigned)incl; // total runs in segment

    int hsum = nh;
#pragma unroll
    for (int off = 32; off; off >>= 1) hsum += __shfl_down(hsum, off, 64);
    if (lane == 0) wpcnt[seg] = (unsigned)hsum; // total hits in segment

    // pass 2: write runs
    unsigned* out = runs + (size_t)seg * SEGCAP;
    for (int x = x0; x <= x1; ++x) {
        float dx = cx - ((x + 0.5f) * g.ks0 + g.ko0);
        float dx2 = dx * dx;
        for (int y = y0; y <= y1; ++y) {
            float dy = cy - ((y + 0.5f) * g.ks1 + g.ko1);
            float dxy = dx2 + dy * dy;
            int zf = -1, zc = 0;
            for (int z = z0; z <= z1; ++z) {
                float dz = cz - ((z + 0.5f) * g.ks2 + g.ko2);
                if (sqrtf(dxy + dz * dz) < g.T) { if (!zc) zf = z; zc++; }
            }
            if (zc) {
                if (w < SEGCAP)
                    out[w] = ((unsigned)l << 16)
                           | ((unsigned)((x << 8) | (y << 4) | zf) << 4)
                           | (unsigned)(zc - 1);
                w++;
            }
        }
    }
}

// Fused gather: one block per (group g, channel c). Group g=0 -> batches {0,3},
// g=1 -> {1,2}; combos {n0, n1, 4+n0, 4+n1} form a closed set over rows
// {q[n0,c], q[n1,c], k[n0,c], k[n1,c]} -> each row staged ONCE globally.
// k rows stored as per-(x,y)-cell exclusive z-prefix sums (stride 17,
// conflict-free): run sum = pk[zf+len] - pk[zf]. 8 threads per segment.
// Per-block partials -> Spart (plain stores, no atomics).
__global__ void __launch_bounds__(512) gather_fused(
        const float* __restrict__ q, const float* __restrict__ k,
        const unsigned* __restrict__ wcnt, const unsigned* __restrict__ runs,
        float* __restrict__ Spart) {
    // sh layout: qa[4096] | qb[4096] | pkA[PKROW] | pkB[PKROW] | sred[32]
    __shared__ float sh[2 * LVOX + 2 * PKROW + 32];
    const int QA = 0, QB = LVOX, PK = 2 * LVOX, SR = 2 * LVOX + 2 * PKROW;

    int g = blockIdx.x;              // 0 or 1
    int c = blockIdx.y;
    int n0 = g ? 1 : 0;
    int n1 = 3 - n0;
    int t = threadIdx.x;

    // stage q rows (coalesced float4)
    const float* q0 = q + ((size_t)(n0 * NCH + c)) * LVOX;
    const float* q1 = q + ((size_t)(n1 * NCH + c)) * LVOX;
#pragma unroll
    for (int i = 0; i < 2; ++i) {
        int off = (t + 512 * i) * 4;
        *(float4*)&sh[QA + off] = *(const float4*)&q0[off];
        *(float4*)&sh[QB + off] = *(const float4*)&q1[off];
    }

    // stage k rows as exclusive z-prefix per cell: thread t owns one cell
    {
        int row = t >> 8;            // 0 -> k[n0], 1 -> k[n1]
        int cl  = t & 255;
        const float* ks = k + ((size_t)((row ? n1 : n0) * NCH + c)) * LVOX + cl * 16;
        float4 v0 = *(const float4*)&ks[0];
        float4 v1 = *(const float4*)&ks[4];
        float4 v2 = *(const float4*)&ks[8];
        float4 v3 = *(const float4*)&ks[12];
        float vv[16] = {v0.x, v0.y, v0.z, v0.w, v1.x, v1.y, v1.z, v1.w,
                        v2.x, v2.y, v2.z, v2.w, v3.x, v3.y, v3.z, v3.w};
        float* dst = &sh[PK + row * PKROW + cl * PKSTR];
        float e = 0.f;
        dst[0] = 0.f;
#pragma unroll
        for (int i = 0; i < 16; ++i) { e += vv[i]; dst[i + 1] = e; }
    }
    __syncthreads();

    const int jl[4]   = {n0, n1, 4 + n0, 4 + n1};
    const int qoff[4] = {QA, QB, QB, QA};              // combo 4+n uses q[3-n]
    const int koff[4] = {PK, PK + PKROW, PK, PK + PKROW};
    float accv[4];

    int segi = t >> 3;               // 0..63: segment within combo
    int tin  = t & 7;                // 8 threads per segment

#pragma unroll
    for (int ci = 0; ci < 4; ++ci) {
        int j = jl[ci];
        unsigned cnt = wcnt[j * NSEG + segi];
        if (cnt > SEGCAP) cnt = SEGCAP;
        const unsigned* rl = runs + (size_t)(j * NSEG + segi) * SEGCAP;
        int qb = qoff[ci], kb = koff[ci];
        float acc = 0.f;
        for (unsigned p = (unsigned)tin * 4u; p < cnt; p += 32u) {
            uint4 r4 = *(const uint4*)&rl[p];   // p%4==0, p+3 < SEGCAP -> in-bounds
            unsigned rr[4] = {r4.x, r4.y, r4.z, r4.w};
#pragma unroll
            for (int e = 0; e < 4; ++e) {
                bool valid = (p + (unsigned)e) < cnt;
                unsigned pr = rr[e];
                int l    = (int)((pr >> 16) & 4095u);   // masked: tail-safe
                int cell = (int)((pr >> 8) & 255u);
                int zf   = (int)((pr >> 4) & 15u);
                int len  = (int)(pr & 15u) + 1;
                float s = sh[kb + cell * PKSTR + zf + len] - sh[kb + cell * PKSTR + zf];
                acc += valid ? sh[qb + l] * s : 0.f;
            }
        }
        accv[ci] = acc;
    }

    int wv = t >> 6, lane = t & 63;
#pragma unroll
    for (int ci = 0; ci < 4; ++ci) {
        float a = accv[ci];
#pragma unroll
        for (int off = 32; off; off >>= 1) a += __shfl_down(a, off, 64);
        if (lane == 0) sh[SR + wv * 4 + ci] = a;
    }
    __syncthreads();
    if (t < 4) {
        float v = 0.f;
#pragma unroll
        for (int w = 0; w < 8; ++w) v += sh[SR + w * 4 + t];
        Spart[(size_t)jl[t] * NBLK + (c * 2 + g)] = v;
    }
}

// Sum Spart over each combo's 320 written slots and wpcnt over 64 segments.
__global__ void finalize(const float* __restrict__ Spart,
                         const unsigned* __restrict__ wpcnt,
                         float* __restrict__ out) {
    __shared__ float tj[NCOMBO];
    int j = threadIdx.x >> 5;      // 8 combos x 32 threads
    int s = threadIdx.x & 31;
    int nn = j & 3;
    int gj = (nn == 1 || nn == 2) ? 1 : 0;
    float v = 0.f;
    for (int i = s; i < NCH; i += 32)
        v += Spart[(size_t)j * NBLK + i * 2 + gj];
    unsigned pc = wpcnt[j * NSEG + s] + wpcnt[j * NSEG + s + 32];
    float pcf = (float)pc;
#pragma unroll
    for (int off = 16; off; off >>= 1) {
        v   += __shfl_down(v, off, 32);
        pcf += __shfl_down(pcf, off, 32);
    }
    if (s == 0) tj[j] = v / (pcf + 1e-6f);
    __syncthreads();
    if (threadIdx.x == 0) {
        float t = 0.f;
#pragma unroll
        for (int jj = 0; jj < NCOMBO; ++jj) t += tj[jj];
        out[0] = -0.5f * t;   // -2*mean over 4 batches, x2 branches
    }
}

extern "C" void kernel_launch(void* const* d_in, const int* in_sizes, int n_in,
                              void* d_out, int out_size, void* d_ws, size_t ws_size,
                              hipStream_t stream) {
    const float* q       = (const float*)d_in[0];
    const float* k       = (const float*)d_in[1];
    const float* coord_q = (const float*)d_in[2];
    const float* coord_k = (const float*)d_in[3];
    float* out = (float*)d_out;

    unsigned* wcnt  = (unsigned*)d_ws;
    unsigned* wpcnt = (unsigned*)((char*)d_ws + WPCNT_OFF);
    float*    Spart = (float*)((char*)d_ws + SPART_OFF);
    unsigned* runs  = (unsigned*)((char*)d_ws + RUNS_OFF);
    // runs needs 8*64*4096*4 B = 8 MB; ws is ~268 MB. No zeroing required:
    // every consumed ws word is deterministically written first.

    enum_runs<<<(NCOMBO * LVOX) / 256, 256, 0, stream>>>(coord_q, coord_k, wcnt, wpcnt, runs);
    gather_fused<<<dim3(2, NCH), 512, 0, stream>>>(q, k, wcnt, runs, Spart);
    finalize<<<1, 256, 0, stream>>>(Spart, wpcnt, out);
}